// Round 1
// baseline (44.354 us; speedup 1.0000x reference)
//
#include <hip/hip_runtime.h>

#define K 3

// Zero the whole output buffer with float4 stores (out_size divisible by 4 here,
// but handle tail generically).
__global__ void zero_fill(float* __restrict__ out, long long n4, long long n) {
    long long i = (long long)blockIdx.x * blockDim.x + threadIdx.x;
    long long stride = (long long)gridDim.x * blockDim.x;
    float4 z = make_float4(0.f, 0.f, 0.f, 0.f);
    float4* o4 = (float4*)out;
    for (long long j = i; j < n4; j += stride) o4[j] = z;
    long long tail = n4 * 4;
    for (long long j = tail + i; j < n; j += stride) out[j] = 0.f;
}

// knots: t[0..K]=x[0]; t[K+1+i]= (x[i+1]+x[i+2]+x[i+3])/3 for i in [0, N-K-2];
// t[N..N+K]=x[N-1].  nk = N+K+1.
__global__ void knots_kernel(const float* __restrict__ x, float* __restrict__ t_out,
                             float* __restrict__ t_ws, int N) {
    int j = blockIdx.x * blockDim.x + threadIdx.x;
    int nk = N + K + 1;
    if (j >= nk) return;
    float v;
    if (j <= K) {
        v = x[0];
    } else if (j >= N) {
        v = x[N - 1];
    } else {
        int i = j - (K + 1);
        v = (x[i + 1] + x[i + 2] + x[i + 3]) / 3.0f;
    }
    t_out[j] = v;
    t_ws[j] = v;
}

// Per-point windowed Cox–de Boor with safe_div (0-den -> 0) semantics,
// exactly mirroring the reference recursion on the 4-wide nonzero window.
__global__ void basis_kernel(const float* __restrict__ x, const float* __restrict__ t,
                             float* __restrict__ Bout, float* __restrict__ vals_ws,
                             int* __restrict__ j0_ws, int N) {
    int i = blockIdx.x * blockDim.x + threadIdx.x;
    if (i >= N) return;
    float xi = x[i];
    int nk = N + K + 1;

    // largest j with t[j] <= xi  (binary search: first index with t[j] > xi, minus 1)
    int lo = 0, hi = nk;
    while (lo < hi) { int mid = (lo + hi) >> 1; if (t[mid] <= xi) lo = mid + 1; else hi = mid; }
    int j0 = lo - 1;
    if (j0 > N - 1) j0 = N - 1;   // x >= t[-2] override -> last basis column
    if (j0 < K) j0 = K;           // defensive; x >= x[0] guarantees j0 >= K
    int c0 = j0 - K;

    float b[K + 2];
    #pragma unroll
    for (int w = 0; w < K + 2; ++w) b[w] = 0.f;
    b[K] = 1.f;   // degree-0: column j0

    #pragma unroll
    for (int d = 1; d <= K; ++d) {
        float nb[K + 1];
        #pragma unroll
        for (int w = 0; w <= K; ++w) {
            int j = c0 + w;
            float tj   = t[j];
            float tjd  = t[j + d];
            float tj1  = t[j + 1];
            float tjd1 = t[j + d + 1];
            float denL = tjd - tj;
            float L = (denL == 0.f) ? 0.f : (xi - tj) / denL;
            float denR = tjd1 - tj1;
            float R = (denR == 0.f) ? 0.f : (tjd1 - xi) / denR;
            nb[w] = L * b[w] + R * b[w + 1];
        }
        #pragma unroll
        for (int w = 0; w <= K; ++w) b[w] = nb[w];
        // b[K+1] stays 0 (column j0+1 is zero at every degree)
    }

    j0_ws[i] = j0;
    #pragma unroll
    for (int w = 0; w <= K; ++w) {
        vals_ws[i * (K + 1) + w] = b[w];
        Bout[(long long)i * N + (c0 + w)] = b[w];
    }
}

// Band gather: (B^T B)[ci][cj] nonzero only for |ci-cj|<=K. Rows containing
// column ci are the contiguous range with j0 in [ci, ci+K] (j0 non-decreasing).
__global__ void btb_kernel(const float* __restrict__ vals, const int* __restrict__ j0arr,
                           const float* __restrict__ s_ptr, float* __restrict__ BTB, int N) {
    int ci = blockIdx.x * blockDim.x + threadIdx.x;
    if (ci >= N) return;

    // rlo = first r with j0[r] >= ci ; rhi = first r with j0[r] >= ci+K+1
    int lo = 0, hi = N;
    while (lo < hi) { int mid = (lo + hi) >> 1; if (j0arr[mid] < ci) lo = mid + 1; else hi = mid; }
    int rlo = lo;
    hi = N;
    int target = ci + K + 1;
    while (lo < hi) { int mid = (lo + hi) >> 1; if (j0arr[mid] < target) lo = mid + 1; else hi = mid; }
    int rhi = lo;

    float acc[K + 1] = {0.f, 0.f, 0.f, 0.f};
    for (int r = rlo; r < rhi; ++r) {
        int c0r = j0arr[r] - K;
        int wi = ci - c0r;                      // guaranteed in [0, K]
        float v = vals[r * (K + 1) + wi];
        #pragma unroll
        for (int o = 0; o <= K; ++o) {
            int wj = wi + o;
            if (wj <= K) acc[o] += v * vals[r * (K + 1) + wj];
        }
    }

    float s = *s_ptr;
    long long base = (long long)ci * N;
    BTB[base + ci] = acc[0] + s;
    #pragma unroll
    for (int o = 1; o <= K; ++o) {
        if (ci + o < N) {
            BTB[base + ci + o] = acc[o];
            BTB[(long long)(ci + o) * N + ci] = acc[o];
        }
    }
}

extern "C" void kernel_launch(void* const* d_in, const int* in_sizes, int n_in,
                              void* d_out, int out_size, void* d_ws, size_t ws_size,
                              hipStream_t stream) {
    const float* x = (const float*)d_in[0];
    const float* s = (const float*)d_in[1];
    int N = in_sizes[0];            // 4096
    int nk = N + K + 1;             // 4100

    float* out = (float*)d_out;
    float* out_knots = out;
    float* out_B = out + nk;
    float* out_BTB = out_B + (long long)N * N;

    // workspace: t (nk floats) | vals (N*(K+1) floats) | j0 (N ints)  ~ 98 KB
    float* t_ws = (float*)d_ws;
    float* vals_ws = t_ws + nk;
    int* j0_ws = (int*)(vals_ws + (long long)N * (K + 1));

    long long total = (long long)out_size;
    long long n4 = total / 4;
    zero_fill<<<2048, 256, 0, stream>>>(out, n4, total);

    int tb = 256;
    knots_kernel<<<(nk + tb - 1) / tb, tb, 0, stream>>>(x, out_knots, t_ws, N);
    basis_kernel<<<(N + tb - 1) / tb, tb, 0, stream>>>(x, t_ws, out_B, vals_ws, j0_ws, N);
    btb_kernel<<<(N + tb - 1) / tb, tb, 0, stream>>>(vals_ws, j0_ws, s, out_BTB, N);
}